// Round 10
// baseline (246.048 us; speedup 1.0000x reference)
//
#include <hip/hip_runtime.h>
#include <math.h>

#define L_MAX 3
#define RCUT 5.0f
#define NB 8
#define NCH 16
#define KDIM 64
#define LMDIM 16   // sum (2l+1), l=0..3
#define GSTRIDE 40 // per-edge geometry floats: sh[16], b[8], R[16]

// ---------------- compile-time Clebsch-Gordan (mirrors reference _real_cg) ----------------
struct CD { double re; double im; };
struct UMat { CD m[7][7]; };
struct CGT { float v[7][7][7]; };

constexpr double cfact(int n){ double r=1.0; for(int i=2;i<=n;++i) r*=(double)i; return r; }
constexpr double cfabs(double x){ return x<0.0 ? -x : x; }
constexpr double csqrt_(double x){
  if (x<=0.0) return 0.0;
  double g = x>1.0 ? x : 1.0;
  for (int i=0;i<100;++i) g = 0.5*(g + x/g);
  return g;
}
constexpr double clebsch(int j1,int m1,int j2,int m2,int J,int M){
  if (m1+m2!=M) return 0.0;
  int ad = j1-j2; if (ad<0) ad=-ad;
  if (J<ad || J>j1+j2) return 0.0;
  double pref = csqrt_((2.0*J+1.0)*cfact(J+j1-j2)*cfact(J-j1+j2)*cfact(j1+j2-J)/cfact(j1+j2+J+1));
  pref *= csqrt_(cfact(J+M)*cfact(J-M)*cfact(j1-m1)*cfact(j1+m1)*cfact(j2-m2)*cfact(j2+m2));
  double s=0.0;
  for (int k=0;k<=j1+j2-J;++k){
    int d0=k,d1=j1+j2-J-k,d2=j1-m1-k,d3=j2+m2-k,d4=J-j2+m1+k,d5=J-j1-m2+k;
    if (d0<0||d1<0||d2<0||d3<0||d4<0||d5<0) continue;
    double den = cfact(d0)*cfact(d1)*cfact(d2)*cfact(d3)*cfact(d4)*cfact(d5);
    s += ((k&1)? -1.0:1.0)/den;
  }
  return pref*s;
}
constexpr UMat u_real(int l){
  UMat U{};
  U.m[l][l] = CD{1.0, 0.0};
  double is2 = csqrt_(0.5);
  for (int mm=1; mm<=l; ++mm){
    double sgn = (mm&1)? -1.0: 1.0;
    U.m[l+mm][l+mm] = CD{sgn*is2, 0.0};
    U.m[l+mm][l-mm] = CD{is2, 0.0};
    U.m[l-mm][l-mm] = CD{0.0, is2};
    U.m[l-mm][l+mm] = CD{0.0, -sgn*is2};
  }
  return U;
}
constexpr CGT real_cg(int l1,int l2,int L){
  double Cc[7][7][7] = {};
  for (int m1=-l1;m1<=l1;++m1)
    for (int m2=-l2;m2<=l2;++m2){
      int M=m1+m2;
      if (M>=-L && M<=L) Cc[l1+m1][l2+m2][L+M] = clebsch(l1,m1,l2,m2,L,M);
    }
  UMat U1=u_real(l1), U2=u_real(l2), U3=u_real(L);
  double Tre[7][7][7]={}, Tim[7][7][7]={};
  for (int a=0;a<2*l1+1;++a)
   for (int m=0;m<2*l1+1;++m){
     CD u1=U1.m[a][m];
     if (u1.re==0.0 && u1.im==0.0) continue;
     for (int b=0;b<2*l2+1;++b)
      for (int n=0;n<2*l2+1;++n){
        CD u2=U2.m[b][n];
        if (u2.re==0.0 && u2.im==0.0) continue;
        CD u12 = CD{u1.re*u2.re-u1.im*u2.im, u1.re*u2.im+u1.im*u2.re};
        for (int c=0;c<2*L+1;++c)
         for (int o=0;o<2*L+1;++o){
           CD u3=U3.m[c][o];
           if (u3.re==0.0 && u3.im==0.0) continue;
           double cc=Cc[m][n][o];
           if (cc==0.0) continue;
           double tr = u12.re*u3.re + u12.im*u3.im;   // u12 * conj(u3)
           double ti = u12.im*u3.re - u12.re*u3.im;
           Tre[a][b][c] += tr*cc;
           Tim[a][b][c] += ti*cc;
         }
      }
   }
  double sre=0.0, sim=0.0;
  for (int a=0;a<2*l1+1;++a) for (int b=0;b<2*l2+1;++b) for (int c=0;c<2*L+1;++c){
    sre += cfabs(Tre[a][b][c]); sim += cfabs(Tim[a][b][c]);
  }
  CGT out{};
  bool ure = (sre>=sim);
  for (int a=0;a<2*l1+1;++a) for (int b=0;b<2*l2+1;++b) for (int c=0;c<2*L+1;++c)
    out.v[a][b][c] = (float)(ure? Tre[a][b][c] : Tim[a][b][c]);
  return out;
}

// A[M][j] = sum_i Cflat[M*16+j][i]*sh[i], MP_SCALING 0.5 folded in (second MP only).
struct alignas(64) CFlat { float v[256][16]; };
constexpr CFlat build_cflat(){
  CFlat o{};
  for (int l1=0;l1<=3;++l1)
   for (int l2=0;l2<=3;++l2){
     int lo = l1>l2 ? l1-l2 : l2-l1;
     int hi = (l1+l2<3)? l1+l2 : 3;
     for (int L=lo; L<=hi; ++L){
       CGT cg = real_cg(l1,l2,L);
       for (int i=0;i<2*l1+1;++i)
        for (int j=0;j<2*l2+1;++j)
         for (int m=0;m<2*L+1;++m){
           o.v[(L*L+m)*16 + (l2*l2+j)][l1*l1+i] += 0.5f*cg.v[i][j][m];
         }
     }
   }
  return o;
}
__device__ const CFlat CFLAT = build_cflat();

// symmetrized dense CG for f (x) f tensor product (NO scaling): only i<=j iterated.
struct CSym { float v[16][16][16]; };
constexpr CSym build_csym(){
  CSym o{};
  for (int l1=0;l1<=3;++l1)
   for (int l2=0;l2<=3;++l2){
     int lo = l1>l2 ? l1-l2 : l2-l1;
     int hi = (l1+l2<3)? l1+l2 : 3;
     for (int L=lo; L<=hi; ++L){
       CGT cg = real_cg(l1,l2,L);
       for (int i=0;i<2*l1+1;++i)
        for (int j=0;j<2*l2+1;++j)
         for (int m=0;m<2*L+1;++m)
           o.v[L*L+m][l1*l1+i][l2*l2+j] += cg.v[i][j][m];
     }
   }
  for (int M=0;M<16;++M)
   for (int i=0;i<16;++i)
    for (int j=i+1;j<16;++j){
      o.v[M][i][j] += o.v[M][j][i];
      o.v[M][j][i] = 0.0f;
    }
  return o;
}

template<int M>
__device__ __forceinline__ float tp_row(const float* __restrict__ f){
  constexpr CSym CS = build_csym();
  float g = 0.0f;
  #pragma unroll
  for (int i=0;i<16;++i)
  #pragma unroll
  for (int j=i;j<16;++j){
    float c = CS.v[M][i][j];
    if (c != 0.0f) g += c * f[i] * f[j];
  }
  return g;
}

template<int l>
__device__ __forceinline__ float inv_term(const float* m){
  constexpr CGT cg = real_cg(l,l,0);
  float a=0.0f;
  #pragma unroll
  for (int i=0;i<2*l+1;++i)
  #pragma unroll
  for (int j=0;j<2*l+1;++j){
    float c = cg.v[i][j][0];
    if (c != 0.0f) a += c*m[l*l+i]*m[l*l+j];
  }
  return a;
}

// ---------------- geometry ----------------
__device__ __forceinline__ void compute_sh(float x, float y, float z, float* sh){
  sh[0]  = 0.28209479177387814f;
  sh[1]  = 0.4886025119029199f*y;
  sh[2]  = 0.4886025119029199f*z;
  sh[3]  = 0.4886025119029199f*x;
  sh[4]  = 1.0925484305920792f*x*y;
  sh[5]  = 1.0925484305920792f*y*z;
  sh[6]  = 0.31539156525252005f*(3.0f*z*z-1.0f);
  sh[7]  = 1.0925484305920792f*x*z;
  sh[8]  = 0.5462742152960396f*(x*x-y*y);
  sh[9]  = 0.5900435899266435f*y*(3.0f*x*x-y*y);
  sh[10] = 2.890611442640554f*x*y*z;
  sh[11] = 0.4570457994644658f*y*(5.0f*z*z-1.0f);
  sh[12] = 0.3731763325901154f*z*(5.0f*z*z-3.0f);
  sh[13] = 0.4570457994644658f*x*(5.0f*z*z-1.0f);
  sh[14] = 1.445305721320277f*z*(x*x-y*y);
  sh[15] = 0.5900435899266435f*x*(x*x-3.0f*y*y);
}

// ---------------- CSR build with distance filter ----------------
__global__ __launch_bounds__(256) void k_hist_d(
    const float* __restrict__ pos, const int* __restrict__ senders,
    const int* __restrict__ recv, int* __restrict__ counts, int E)
{
  int e = blockIdx.x*256 + threadIdx.x;
  if (e >= E) return;
  int s = senders[e], r = recv[e];
  float dx = pos[r*3+0]-pos[s*3+0];
  float dy = pos[r*3+1]-pos[s*3+1];
  float dz = pos[r*3+2]-pos[s*3+2];
  float d  = sqrtf(dx*dx+dy*dy+dz*dz + 1e-12f);
  if (d < RCUT) atomicAdd(&counts[r], 1);
}

__global__ __launch_bounds__(256) void k_scan1(const int* __restrict__ counts,
                                               int* __restrict__ offsets,
                                               int* __restrict__ bsum, int N){
  __shared__ int buf[256];
  int i = blockIdx.x*256 + threadIdx.x;
  int v = (i<N)? counts[i] : 0;
  buf[threadIdx.x] = v;
  __syncthreads();
  #pragma unroll
  for (int o=1;o<256;o<<=1){
    int t = (threadIdx.x>=o)? buf[threadIdx.x-o] : 0;
    __syncthreads();
    buf[threadIdx.x] += t;
    __syncthreads();
  }
  if (i<N) offsets[i] = buf[threadIdx.x] - v;      // local exclusive
  if (threadIdx.x==255) bsum[blockIdx.x] = buf[255];
}

__global__ __launch_bounds__(256) void k_scan2(const int* __restrict__ bsum,
                                               int* __restrict__ bbase, int SB){
  __shared__ int buf[256];
  int v = (threadIdx.x<SB)? bsum[threadIdx.x] : 0;
  buf[threadIdx.x] = v;
  __syncthreads();
  #pragma unroll
  for (int o=1;o<256;o<<=1){
    int t = (threadIdx.x>=o)? buf[threadIdx.x-o] : 0;
    __syncthreads();
    buf[threadIdx.x] += t;
    __syncthreads();
  }
  if (threadIdx.x<SB) bbase[threadIdx.x] = buf[threadIdx.x] - v;
}

__global__ __launch_bounds__(256) void k_scan3(int* __restrict__ offsets,
                                               const int* __restrict__ bbase, int N){
  int i = blockIdx.x*256 + threadIdx.x;
  if (i<N) offsets[i] += bbase[blockIdx.x];
}

// thread per edge: filter, claim slot, precompute geometry into bucket-ordered arrays
__global__ __launch_bounds__(256) void k_geom(
    const float* __restrict__ pos, const float* __restrict__ Winv,
    const int* __restrict__ species,
    const int* __restrict__ senders, const int* __restrict__ recv,
    const int* __restrict__ offsets, int* __restrict__ cursor,
    int* __restrict__ bucket_s, float* __restrict__ geomArr, int E)
{
  int e = blockIdx.x*256 + threadIdx.x;
  if (e >= E) return;
  int s = senders[e], r = recv[e];
  float dx = pos[r*3+0]-pos[s*3+0];
  float dy = pos[r*3+1]-pos[s*3+1];
  float dz = pos[r*3+2]-pos[s*3+2];
  float d  = sqrtf(dx*dx+dy*dy+dz*dz + 1e-12f);
  if (d >= RCUT) return;
  int p = atomicAdd(&cursor[r], 1);
  int slot = offsets[r] + p;
  float inv_d = 1.0f/d;
  float sh[16];
  compute_sh(dx*inv_d, dy*inv_d, dz*inv_d, sh);
  float fc = 0.5f*(cosf(d*(3.14159265358979323846f/RCUT))+1.0f);
  float b[8];
  #pragma unroll
  for (int q=0;q<NB;++q){
    float t = (d - (float)((double)q*(5.0/7.0))) * 1.6f;  // sigma=0.625
    b[q] = expf(-0.5f*t*t)*fc;
  }
  float* g = geomArr + (size_t)slot*GSTRIDE;
  #pragma unroll
  for (int i=0;i<16;++i) g[i] = sh[i];
  #pragma unroll
  for (int q=0;q<8;++q) g[16+q] = b[q];
  #pragma unroll
  for (int l=0;l<4;++l)
    #pragma unroll
    for (int n=0;n<4;++n){
      float acc=0.0f;
      #pragma unroll
      for (int q=0;q<NB;++q) acc += b[q]*Winv[l*32+q*4+n];
      g[24+l*4+n] = acc;
    }
  bucket_s[slot] = s | (species[s]<<16);   // N=10000 < 2^16
}

// ---------------- kernel A: ONE-WAVE BLOCK, TWO atoms interleaved (chain QD x2) ----------------
__global__ __launch_bounds__(64) void kA_gather_tp(
    const float* __restrict__ emb, const int* __restrict__ species,
    const int* __restrict__ offsets, const int* __restrict__ counts,
    const int* __restrict__ bucket_s, const float* __restrict__ geomArr,
    float* __restrict__ feats, int N)
{
  int r0 = blockIdx.x*2;
  int r1 = r0 + 1;
  if (r0 >= N) return;
  bool has1 = (r1 < N);
  int lane = threadIdx.x;
  int n = lane>>4, c = lane&15;
  int off0 = offsets[r0], cnt0 = counts[r0];
  int off1 = has1? offsets[r1] : 0, cnt1 = has1? counts[r1] : 0;
  float f0[16], f1[16];
  #pragma unroll
  for (int lm=0; lm<16; ++lm){ f0[lm]=0.0f; f1[lm]=0.0f; }

  int maxc = cnt0 > cnt1 ? cnt0 : cnt1;
  for (int j=0; j<maxc; ++j){
    bool a0 = (j<cnt0), a1 = (j<cnt1);
    // ---- load phase: both atoms' loads issued before either compute ----
    float e50=0, R00=0,R01=0,R02=0,R03=0;
    float4 s00{},s01{},s02{},s03{};
    if (a0){
      int pk = bucket_s[off0+j];
      e50 = 0.5f*emb[(pk>>16)*NCH+c];
      const float* gm = geomArr + (size_t)(off0+j)*GSTRIDE;
      s00=*(const float4*)(gm+0); s01=*(const float4*)(gm+4);
      s02=*(const float4*)(gm+8); s03=*(const float4*)(gm+12);
      R00=gm[24+0+n]; R01=gm[24+4+n]; R02=gm[24+8+n]; R03=gm[24+12+n];
    }
    float e51=0, R10=0,R11=0,R12=0,R13=0;
    float4 s10{},s11{},s12{},s13{};
    if (a1){
      int pk = bucket_s[off1+j];
      e51 = 0.5f*emb[(pk>>16)*NCH+c];
      const float* gm = geomArr + (size_t)(off1+j)*GSTRIDE;
      s10=*(const float4*)(gm+0); s11=*(const float4*)(gm+4);
      s12=*(const float4*)(gm+8); s13=*(const float4*)(gm+12);
      R10=gm[24+0+n]; R11=gm[24+4+n]; R12=gm[24+8+n]; R13=gm[24+12+n];
    }
    // ---- compute phase ----
    if (a0){
      float t0=R00*e50, t1=R01*e50, t2=R02*e50, t3=R03*e50;
      f0[0] += s00.x*t0;
      f0[1] += s00.y*t1;  f0[2] += s00.z*t1;  f0[3] += s00.w*t1;
      f0[4] += s01.x*t2;  f0[5] += s01.y*t2;  f0[6] += s01.z*t2;  f0[7] += s01.w*t2;  f0[8] += s02.x*t2;
      f0[9] += s02.y*t3;  f0[10]+= s02.z*t3;  f0[11]+= s02.w*t3;
      f0[12]+= s03.x*t3;  f0[13]+= s03.y*t3;  f0[14]+= s03.z*t3;  f0[15]+= s03.w*t3;
    }
    if (a1){
      float t0=R10*e51, t1=R11*e51, t2=R12*e51, t3=R13*e51;
      f1[0] += s10.x*t0;
      f1[1] += s10.y*t1;  f1[2] += s10.z*t1;  f1[3] += s10.w*t1;
      f1[4] += s11.x*t2;  f1[5] += s11.y*t2;  f1[6] += s11.z*t2;  f1[7] += s11.w*t2;  f1[8] += s12.x*t2;
      f1[9] += s12.y*t3;  f1[10]+= s12.z*t3;  f1[11]+= s12.w*t3;
      f1[12]+= s13.x*t3;  f1[13]+= s13.y*t3;  f1[14]+= s13.z*t3;  f1[15]+= s13.w*t3;
    }
  }
  // symmetric tensor product + embed
  {
    float g[16];
    g[0]=tp_row<0>(f0);  g[1]=tp_row<1>(f0);  g[2]=tp_row<2>(f0);  g[3]=tp_row<3>(f0);
    g[4]=tp_row<4>(f0);  g[5]=tp_row<5>(f0);  g[6]=tp_row<6>(f0);  g[7]=tp_row<7>(f0);
    g[8]=tp_row<8>(f0);  g[9]=tp_row<9>(f0);  g[10]=tp_row<10>(f0); g[11]=tp_row<11>(f0);
    g[12]=tp_row<12>(f0); g[13]=tp_row<13>(f0); g[14]=tp_row<14>(f0); g[15]=tp_row<15>(f0);
    float ek = emb[species[r0]*NCH + c];
    float* fp = feats + (size_t)r0*(LMDIM*KDIM) + lane;
    #pragma unroll
    for (int lm=0; lm<16; ++lm) fp[lm*KDIM] = (f0[lm] + g[lm])*ek;
  }
  if (has1){
    float g[16];
    g[0]=tp_row<0>(f1);  g[1]=tp_row<1>(f1);  g[2]=tp_row<2>(f1);  g[3]=tp_row<3>(f1);
    g[4]=tp_row<4>(f1);  g[5]=tp_row<5>(f1);  g[6]=tp_row<6>(f1);  g[7]=tp_row<7>(f1);
    g[8]=tp_row<8>(f1);  g[9]=tp_row<9>(f1);  g[10]=tp_row<10>(f1); g[11]=tp_row<11>(f1);
    g[12]=tp_row<12>(f1); g[13]=tp_row<13>(f1); g[14]=tp_row<14>(f1); g[15]=tp_row<15>(f1);
    float ek = emb[species[r1]*NCH + c];
    float* fp = feats + (size_t)r1*(LMDIM*KDIM) + lane;
    #pragma unroll
    for (int lm=0; lm<16; ++lm) fp[lm*KDIM] = (f1[lm] + g[lm])*ek;
  }
}

// ---------------- kernel B: ONE-WAVE BLOCK, TWO atoms interleaved + shared dual MLP ----------
__global__ __launch_bounds__(64) void kB_mp2_mlp(
    const float* __restrict__ Weq,
    const float* __restrict__ W1, const float* __restrict__ W2,
    const float* __restrict__ wl,
    const int* __restrict__ offsets, const int* __restrict__ counts,
    const int* __restrict__ bucket_s, const float* __restrict__ geomArr,
    const float* __restrict__ embedded, float* __restrict__ eatom, int N)
{
  __shared__ __align__(16) float Ash[512];  // 2 KB: A0 [0:256], A1 [256:512]
  int r0 = blockIdx.x*2;
  int r1 = r0 + 1;
  if (r0 >= N) return;
  bool has1 = (r1 < N);
  int k = threadIdx.x;
  int off0 = offsets[r0], cnt0 = counts[r0];
  int off1 = has1? offsets[r1] : 0, cnt1 = has1? counts[r1] : 0;
  float* A0 = Ash;
  float* A1 = Ash + 256;
  // hoist Weq column k (shared by both atoms)
  float Wq[4][8];
  #pragma unroll
  for (int L=0;L<4;++L)
    #pragma unroll
    for (int q=0;q<8;++q)
      Wq[L][q] = Weq[L*(NB*KDIM) + q*KDIM + k];
  float m0[16], m1[16];
  #pragma unroll
  for (int i=0;i<16;++i){ m0[i]=0.0f; m1[i]=0.0f; }

  int maxc = cnt0 > cnt1 ? cnt0 : cnt1;
  for (int j=0; j<maxc; ++j){
    bool a0 = (j<cnt0), a1 = (j<cnt1);
    // ---- load phase: both chains' gathers in flight together ----
    float nb0[16], sh0[16], Req0[4];
    if (a0){
      int s = bucket_s[off0+j] & 0xFFFF;
      const float* npp = embedded + (size_t)s*(LMDIM*KDIM) + k;
      #pragma unroll
      for (int lm=0; lm<16; ++lm) nb0[lm]=npp[lm*KDIM];
      const float* gm = geomArr + (size_t)(off0+j)*GSTRIDE;
      float4 g0=*(const float4*)(gm+0), g1=*(const float4*)(gm+4);
      float4 g2=*(const float4*)(gm+8), g3=*(const float4*)(gm+12);
      float4 b0=*(const float4*)(gm+16), b1=*(const float4*)(gm+20);
      sh0[0]=g0.x; sh0[1]=g0.y; sh0[2]=g0.z; sh0[3]=g0.w;
      sh0[4]=g1.x; sh0[5]=g1.y; sh0[6]=g1.z; sh0[7]=g1.w;
      sh0[8]=g2.x; sh0[9]=g2.y; sh0[10]=g2.z; sh0[11]=g2.w;
      sh0[12]=g3.x; sh0[13]=g3.y; sh0[14]=g3.z; sh0[15]=g3.w;
      float bb[8] = {b0.x,b0.y,b0.z,b0.w, b1.x,b1.y,b1.z,b1.w};
      #pragma unroll
      for (int L=0;L<4;++L){
        float acc=0.0f;
        #pragma unroll
        for (int q=0;q<8;++q) acc += bb[q]*Wq[L][q];
        Req0[L]=acc;
      }
    }
    float nb1[16], sh1[16], Req1[4];
    if (a1){
      int s = bucket_s[off1+j] & 0xFFFF;
      const float* npp = embedded + (size_t)s*(LMDIM*KDIM) + k;
      #pragma unroll
      for (int lm=0; lm<16; ++lm) nb1[lm]=npp[lm*KDIM];
      const float* gm = geomArr + (size_t)(off1+j)*GSTRIDE;
      float4 g0=*(const float4*)(gm+0), g1=*(const float4*)(gm+4);
      float4 g2=*(const float4*)(gm+8), g3=*(const float4*)(gm+12);
      float4 b0=*(const float4*)(gm+16), b1=*(const float4*)(gm+20);
      sh1[0]=g0.x; sh1[1]=g0.y; sh1[2]=g0.z; sh1[3]=g0.w;
      sh1[4]=g1.x; sh1[5]=g1.y; sh1[6]=g1.z; sh1[7]=g1.w;
      sh1[8]=g2.x; sh1[9]=g2.y; sh1[10]=g2.z; sh1[11]=g2.w;
      sh1[12]=g3.x; sh1[13]=g3.y; sh1[14]=g3.z; sh1[15]=g3.w;
      float bb[8] = {b0.x,b0.y,b0.z,b0.w, b1.x,b1.y,b1.z,b1.w};
      #pragma unroll
      for (int L=0;L<4;++L){
        float acc=0.0f;
        #pragma unroll
        for (int q=0;q<8;++q) acc += bb[q]*Wq[L][q];
        Req1[L]=acc;
      }
    }
    // ---- A build (both; LDS writes batch together) ----
    if (a0){
      #pragma unroll
      for (int q=0;q<4;++q){
        int ent = q*64 + k;
        const float4* c4 = (const float4*)CFLAT.v[ent];
        float4 c0=c4[0], c1=c4[1], c2=c4[2], c3=c4[3];
        A0[ent] = c0.x*sh0[0]+c0.y*sh0[1]+c0.z*sh0[2]+c0.w*sh0[3]
                + c1.x*sh0[4]+c1.y*sh0[5]+c1.z*sh0[6]+c1.w*sh0[7]
                + c2.x*sh0[8]+c2.y*sh0[9]+c2.z*sh0[10]+c2.w*sh0[11]
                + c3.x*sh0[12]+c3.y*sh0[13]+c3.z*sh0[14]+c3.w*sh0[15];
      }
    }
    if (a1){
      #pragma unroll
      for (int q=0;q<4;++q){
        int ent = q*64 + k;
        const float4* c4 = (const float4*)CFLAT.v[ent];
        float4 c0=c4[0], c1=c4[1], c2=c4[2], c3=c4[3];
        A1[ent] = c0.x*sh1[0]+c0.y*sh1[1]+c0.z*sh1[2]+c0.w*sh1[3]
                + c1.x*sh1[4]+c1.y*sh1[5]+c1.z*sh1[6]+c1.w*sh1[7]
                + c2.x*sh1[8]+c2.y*sh1[9]+c2.z*sh1[10]+c2.w*sh1[11]
                + c3.x*sh1[12]+c3.y*sh1[13]+c3.z*sh1[14]+c3.w*sh1[15];
      }
    }
    // ---- matvec (both; single wave so LDS RAW handled by lgkmcnt) ----
    if (a0){
      #pragma unroll
      for (int M=0;M<16;++M){
        const int L = (M==0)?0 : (M<4)?1 : (M<9)?2 : 3;
        const float4* a4 = (const float4*)(A0 + M*16);
        float4 a0v=a4[0], a1v=a4[1], a2v=a4[2], a3v=a4[3];
        float acc = a0v.x*nb0[0]+a0v.y*nb0[1]+a0v.z*nb0[2]+a0v.w*nb0[3]
                  + a1v.x*nb0[4]+a1v.y*nb0[5]+a1v.z*nb0[6]+a1v.w*nb0[7]
                  + a2v.x*nb0[8]+a2v.y*nb0[9]+a2v.z*nb0[10]+a2v.w*nb0[11]
                  + a3v.x*nb0[12]+a3v.y*nb0[13]+a3v.z*nb0[14]+a3v.w*nb0[15];
        m0[M] += acc*Req0[L];
      }
    }
    if (a1){
      #pragma unroll
      for (int M=0;M<16;++M){
        const int L = (M==0)?0 : (M<4)?1 : (M<9)?2 : 3;
        const float4* a4 = (const float4*)(A1 + M*16);
        float4 a0v=a4[0], a1v=a4[1], a2v=a4[2], a3v=a4[3];
        float acc = a0v.x*nb1[0]+a0v.y*nb1[1]+a0v.z*nb1[2]+a0v.w*nb1[3]
                  + a1v.x*nb1[4]+a1v.y*nb1[5]+a1v.z*nb1[6]+a1v.w*nb1[7]
                  + a2v.x*nb1[8]+a2v.y*nb1[9]+a2v.z*nb1[10]+a2v.w*nb1[11]
                  + a3v.x*nb1[12]+a3v.y*nb1[13]+a3v.z*nb1[14]+a3v.w*nb1[15];
        m1[M] += acc*Req1[L];
      }
    }
  }

  // invariants for both atoms
  float inv0 = m0[0] + inv_term<0>(m0) + inv_term<1>(m0) + inv_term<2>(m0) + inv_term<3>(m0);
  float inv1 = m1[0] + inv_term<0>(m1) + inv_term<1>(m1) + inv_term<2>(m1) + inv_term<3>(m1);
  // dual MLP sharing each weight load: [0:64] inv0, [64:128] h0, [128:192] inv1, [192:256] h1
  float* B = Ash;
  B[k] = inv0;
  B[128+k] = inv1;
  float a0s=0.0f, a1s=0.0f;
  #pragma unroll
  for (int c=0;c<64;++c){
    float w = W1[c*64+k];
    a0s += B[c]*w;
    a1s += B[128+c]*w;
  }
  a0s = a0s / (1.0f + expf(-a0s));
  a1s = a1s / (1.0f + expf(-a1s));
  B[64+k]  = a0s;
  B[192+k] = a1s;
  float h20=0.0f, h21=0.0f;
  #pragma unroll
  for (int c=0;c<64;++c){
    float w = W2[c*64+k];
    h20 += B[64+c]*w;
    h21 += B[192+c]*w;
  }
  h20 = h20 / (1.0f + expf(-h20));
  h21 = h21 / (1.0f + expf(-h21));
  float wk = wl[k];
  float e0 = h20*wk, e1 = h21*wk;
  #pragma unroll
  for (int o=32; o>0; o>>=1){
    e0 += __shfl_down(e0, o);
    e1 += __shfl_down(e1, o);
  }
  if (k==0){
    eatom[r0] = e0;
    if (has1) eatom[r1] = e1;
  }
}

__global__ __launch_bounds__(256) void k_reduce(const float* __restrict__ eatom,
                                                float* __restrict__ out, int N){
  __shared__ float buf[256];
  float a=0.0f;
  for (int i=threadIdx.x; i<N; i+=256) a += eatom[i];
  buf[threadIdx.x]=a;
  __syncthreads();
  #pragma unroll
  for (int o=128;o>0;o>>=1){
    if (threadIdx.x<o) buf[threadIdx.x]+=buf[threadIdx.x+o];
    __syncthreads();
  }
  if (threadIdx.x==0) out[0]=buf[0];
}

// ---------------- launch ----------------
extern "C" void kernel_launch(void* const* d_in, const int* in_sizes, int n_in,
                              void* d_out, int out_size, void* d_ws, size_t ws_size,
                              hipStream_t stream)
{
  const float* pos     = (const float*)d_in[0];
  const float* emb     = (const float*)d_in[1];
  const float* Winv    = (const float*)d_in[2];
  const float* Weq     = (const float*)d_in[3];
  const float* W1      = (const float*)d_in[4];
  const float* W2      = (const float*)d_in[5];
  const float* wl      = (const float*)d_in[6];
  const int*   species = (const int*)d_in[7];
  const int*   senders = (const int*)d_in[8];
  const int*   recv    = (const int*)d_in[9];
  int N = in_sizes[7];
  int E = in_sizes[8];

  char* ws = (char*)d_ws;
  float* feats   = (float*)ws;                                   // N*1024 f32
  float* geomArr = feats + (size_t)N*(LMDIM*KDIM);               // E*GSTRIDE f32 (worst case)
  float* eatom   = geomArr + (size_t)E*GSTRIDE;                  // N f32
  int*   counts  = (int*)(eatom + N);                            // N
  int*   cursor  = counts + N;                                   // N
  int*   offsets = cursor + N;                                   // N
  int*   bsum    = offsets + N;                                  // 256
  int*   bbase   = bsum + 256;                                   // 256
  int*   bucket_s= bbase + 256;                                  // E

  hipMemsetAsync(counts, 0, 2*(size_t)N*sizeof(int), stream);    // counts+cursor

  int ebl = (E+255)/256;
  int SB  = (N+255)/256;
  k_hist_d<<<ebl, 256, 0, stream>>>(pos, senders, recv, counts, E);
  k_scan1<<<SB, 256, 0, stream>>>(counts, offsets, bsum, N);
  k_scan2<<<1, 256, 0, stream>>>(bsum, bbase, SB);
  k_scan3<<<SB, 256, 0, stream>>>(offsets, bbase, N);
  k_geom<<<ebl, 256, 0, stream>>>(pos, Winv, species, senders, recv, offsets, cursor,
                                  bucket_s, geomArr, E);
  kA_gather_tp<<<(N+1)/2, 64, 0, stream>>>(emb, species, offsets, counts, bucket_s, geomArr, feats, N);
  kB_mp2_mlp<<<(N+1)/2, 64, 0, stream>>>(Weq, W1, W2, wl, offsets, counts, bucket_s, geomArr,
                                         feats, eatom, N);
  k_reduce<<<1, 256, 0, stream>>>(eatom, (float*)d_out, N);
}

// Round 11
// 231.081 us; speedup vs baseline: 1.0648x; 1.0648x over previous
//
#include <hip/hip_runtime.h>
#include <math.h>

#define L_MAX 3
#define RCUT 5.0f
#define NB 8
#define NCH 16
#define KDIM 64
#define LMDIM 16   // sum (2l+1), l=0..3
#define GSTRIDE 40 // per-edge geometry floats: sh[16], b[8], R[16]

// feats layout is K-MAJOR: feats[atom*1024 + k*16 + lm]  (lm fastest)
// -> per-edge nb gather is 4 dwordx4 per lane from one contiguous 4KB block.

// ---------------- compile-time Clebsch-Gordan (mirrors reference _real_cg) ----------------
struct CD { double re; double im; };
struct UMat { CD m[7][7]; };
struct CGT { float v[7][7][7]; };

constexpr double cfact(int n){ double r=1.0; for(int i=2;i<=n;++i) r*=(double)i; return r; }
constexpr double cfabs(double x){ return x<0.0 ? -x : x; }
constexpr double csqrt_(double x){
  if (x<=0.0) return 0.0;
  double g = x>1.0 ? x : 1.0;
  for (int i=0;i<100;++i) g = 0.5*(g + x/g);
  return g;
}
constexpr double clebsch(int j1,int m1,int j2,int m2,int J,int M){
  if (m1+m2!=M) return 0.0;
  int ad = j1-j2; if (ad<0) ad=-ad;
  if (J<ad || J>j1+j2) return 0.0;
  double pref = csqrt_((2.0*J+1.0)*cfact(J+j1-j2)*cfact(J-j1+j2)*cfact(j1+j2-J)/cfact(j1+j2+J+1));
  pref *= csqrt_(cfact(J+M)*cfact(J-M)*cfact(j1-m1)*cfact(j1+m1)*cfact(j2-m2)*cfact(j2+m2));
  double s=0.0;
  for (int k=0;k<=j1+j2-J;++k){
    int d0=k,d1=j1+j2-J-k,d2=j1-m1-k,d3=j2+m2-k,d4=J-j2+m1+k,d5=J-j1-m2+k;
    if (d0<0||d1<0||d2<0||d3<0||d4<0||d5<0) continue;
    double den = cfact(d0)*cfact(d1)*cfact(d2)*cfact(d3)*cfact(d4)*cfact(d5);
    s += ((k&1)? -1.0:1.0)/den;
  }
  return pref*s;
}
constexpr UMat u_real(int l){
  UMat U{};
  U.m[l][l] = CD{1.0, 0.0};
  double is2 = csqrt_(0.5);
  for (int mm=1; mm<=l; ++mm){
    double sgn = (mm&1)? -1.0: 1.0;
    U.m[l+mm][l+mm] = CD{sgn*is2, 0.0};
    U.m[l+mm][l-mm] = CD{is2, 0.0};
    U.m[l-mm][l-mm] = CD{0.0, is2};
    U.m[l-mm][l+mm] = CD{0.0, -sgn*is2};
  }
  return U;
}
constexpr CGT real_cg(int l1,int l2,int L){
  double Cc[7][7][7] = {};
  for (int m1=-l1;m1<=l1;++m1)
    for (int m2=-l2;m2<=l2;++m2){
      int M=m1+m2;
      if (M>=-L && M<=L) Cc[l1+m1][l2+m2][L+M] = clebsch(l1,m1,l2,m2,L,M);
    }
  UMat U1=u_real(l1), U2=u_real(l2), U3=u_real(L);
  double Tre[7][7][7]={}, Tim[7][7][7]={};
  for (int a=0;a<2*l1+1;++a)
   for (int m=0;m<2*l1+1;++m){
     CD u1=U1.m[a][m];
     if (u1.re==0.0 && u1.im==0.0) continue;
     for (int b=0;b<2*l2+1;++b)
      for (int n=0;n<2*l2+1;++n){
        CD u2=U2.m[b][n];
        if (u2.re==0.0 && u2.im==0.0) continue;
        CD u12 = CD{u1.re*u2.re-u1.im*u2.im, u1.re*u2.im+u1.im*u2.re};
        for (int c=0;c<2*L+1;++c)
         for (int o=0;o<2*L+1;++o){
           CD u3=U3.m[c][o];
           if (u3.re==0.0 && u3.im==0.0) continue;
           double cc=Cc[m][n][o];
           if (cc==0.0) continue;
           double tr = u12.re*u3.re + u12.im*u3.im;   // u12 * conj(u3)
           double ti = u12.im*u3.re - u12.re*u3.im;
           Tre[a][b][c] += tr*cc;
           Tim[a][b][c] += ti*cc;
         }
      }
   }
  double sre=0.0, sim=0.0;
  for (int a=0;a<2*l1+1;++a) for (int b=0;b<2*l2+1;++b) for (int c=0;c<2*L+1;++c){
    sre += cfabs(Tre[a][b][c]); sim += cfabs(Tim[a][b][c]);
  }
  CGT out{};
  bool ure = (sre>=sim);
  for (int a=0;a<2*l1+1;++a) for (int b=0;b<2*l2+1;++b) for (int c=0;c<2*L+1;++c)
    out.v[a][b][c] = (float)(ure? Tre[a][b][c] : Tim[a][b][c]);
  return out;
}

// A[M][j] = sum_i Cflat[M*16+j][i]*sh[i], MP_SCALING 0.5 folded in (second MP only).
struct alignas(64) CFlat { float v[256][16]; };
constexpr CFlat build_cflat(){
  CFlat o{};
  for (int l1=0;l1<=3;++l1)
   for (int l2=0;l2<=3;++l2){
     int lo = l1>l2 ? l1-l2 : l2-l1;
     int hi = (l1+l2<3)? l1+l2 : 3;
     for (int L=lo; L<=hi; ++L){
       CGT cg = real_cg(l1,l2,L);
       for (int i=0;i<2*l1+1;++i)
        for (int j=0;j<2*l2+1;++j)
         for (int m=0;m<2*L+1;++m){
           o.v[(L*L+m)*16 + (l2*l2+j)][l1*l1+i] += 0.5f*cg.v[i][j][m];
         }
     }
   }
  return o;
}
__device__ const CFlat CFLAT = build_cflat();

// symmetrized dense CG for f (x) f tensor product (NO scaling): only i<=j iterated.
struct CSym { float v[16][16][16]; };
constexpr CSym build_csym(){
  CSym o{};
  for (int l1=0;l1<=3;++l1)
   for (int l2=0;l2<=3;++l2){
     int lo = l1>l2 ? l1-l2 : l2-l1;
     int hi = (l1+l2<3)? l1+l2 : 3;
     for (int L=lo; L<=hi; ++L){
       CGT cg = real_cg(l1,l2,L);
       for (int i=0;i<2*l1+1;++i)
        for (int j=0;j<2*l2+1;++j)
         for (int m=0;m<2*L+1;++m)
           o.v[L*L+m][l1*l1+i][l2*l2+j] += cg.v[i][j][m];
     }
   }
  for (int M=0;M<16;++M)
   for (int i=0;i<16;++i)
    for (int j=i+1;j<16;++j){
      o.v[M][i][j] += o.v[M][j][i];
      o.v[M][j][i] = 0.0f;
    }
  return o;
}

template<int M>
__device__ __forceinline__ float tp_row(const float* __restrict__ f){
  constexpr CSym CS = build_csym();
  float g = 0.0f;
  #pragma unroll
  for (int i=0;i<16;++i)
  #pragma unroll
  for (int j=i;j<16;++j){
    float c = CS.v[M][i][j];
    if (c != 0.0f) g += c * f[i] * f[j];
  }
  return g;
}

template<int l>
__device__ __forceinline__ float inv_term(const float* m){
  constexpr CGT cg = real_cg(l,l,0);
  float a=0.0f;
  #pragma unroll
  for (int i=0;i<2*l+1;++i)
  #pragma unroll
  for (int j=0;j<2*l+1;++j){
    float c = cg.v[i][j][0];
    if (c != 0.0f) a += c*m[l*l+i]*m[l*l+j];
  }
  return a;
}

// ---------------- geometry ----------------
__device__ __forceinline__ void compute_sh(float x, float y, float z, float* sh){
  sh[0]  = 0.28209479177387814f;
  sh[1]  = 0.4886025119029199f*y;
  sh[2]  = 0.4886025119029199f*z;
  sh[3]  = 0.4886025119029199f*x;
  sh[4]  = 1.0925484305920792f*x*y;
  sh[5]  = 1.0925484305920792f*y*z;
  sh[6]  = 0.31539156525252005f*(3.0f*z*z-1.0f);
  sh[7]  = 1.0925484305920792f*x*z;
  sh[8]  = 0.5462742152960396f*(x*x-y*y);
  sh[9]  = 0.5900435899266435f*y*(3.0f*x*x-y*y);
  sh[10] = 2.890611442640554f*x*y*z;
  sh[11] = 0.4570457994644658f*y*(5.0f*z*z-1.0f);
  sh[12] = 0.3731763325901154f*z*(5.0f*z*z-3.0f);
  sh[13] = 0.4570457994644658f*x*(5.0f*z*z-1.0f);
  sh[14] = 1.445305721320277f*z*(x*x-y*y);
  sh[15] = 0.5900435899266435f*x*(x*x-3.0f*y*y);
}

// ---------------- CSR build with distance filter ----------------
__global__ __launch_bounds__(256) void k_hist_d(
    const float* __restrict__ pos, const int* __restrict__ senders,
    const int* __restrict__ recv, int* __restrict__ counts, int E)
{
  int e = blockIdx.x*256 + threadIdx.x;
  if (e >= E) return;
  int s = senders[e], r = recv[e];
  float dx = pos[r*3+0]-pos[s*3+0];
  float dy = pos[r*3+1]-pos[s*3+1];
  float dz = pos[r*3+2]-pos[s*3+2];
  float d  = sqrtf(dx*dx+dy*dy+dz*dz + 1e-12f);
  if (d < RCUT) atomicAdd(&counts[r], 1);
}

__global__ __launch_bounds__(256) void k_scan1(const int* __restrict__ counts,
                                               int* __restrict__ offsets,
                                               int* __restrict__ bsum, int N){
  __shared__ int buf[256];
  int i = blockIdx.x*256 + threadIdx.x;
  int v = (i<N)? counts[i] : 0;
  buf[threadIdx.x] = v;
  __syncthreads();
  #pragma unroll
  for (int o=1;o<256;o<<=1){
    int t = (threadIdx.x>=o)? buf[threadIdx.x-o] : 0;
    __syncthreads();
    buf[threadIdx.x] += t;
    __syncthreads();
  }
  if (i<N) offsets[i] = buf[threadIdx.x] - v;      // local exclusive
  if (threadIdx.x==255) bsum[blockIdx.x] = buf[255];
}

__global__ __launch_bounds__(256) void k_scan2(const int* __restrict__ bsum,
                                               int* __restrict__ bbase, int SB){
  __shared__ int buf[256];
  int v = (threadIdx.x<SB)? bsum[threadIdx.x] : 0;
  buf[threadIdx.x] = v;
  __syncthreads();
  #pragma unroll
  for (int o=1;o<256;o<<=1){
    int t = (threadIdx.x>=o)? buf[threadIdx.x-o] : 0;
    __syncthreads();
    buf[threadIdx.x] += t;
    __syncthreads();
  }
  if (threadIdx.x<SB) bbase[threadIdx.x] = buf[threadIdx.x] - v;
}

__global__ __launch_bounds__(256) void k_scan3(int* __restrict__ offsets,
                                               const int* __restrict__ bbase, int N){
  int i = blockIdx.x*256 + threadIdx.x;
  if (i<N) offsets[i] += bbase[blockIdx.x];
}

// thread per edge: filter, claim slot, precompute geometry into bucket-ordered arrays
__global__ __launch_bounds__(256) void k_geom(
    const float* __restrict__ pos, const float* __restrict__ Winv,
    const int* __restrict__ species,
    const int* __restrict__ senders, const int* __restrict__ recv,
    const int* __restrict__ offsets, int* __restrict__ cursor,
    int* __restrict__ bucket_s, float* __restrict__ geomArr, int E)
{
  int e = blockIdx.x*256 + threadIdx.x;
  if (e >= E) return;
  int s = senders[e], r = recv[e];
  float dx = pos[r*3+0]-pos[s*3+0];
  float dy = pos[r*3+1]-pos[s*3+1];
  float dz = pos[r*3+2]-pos[s*3+2];
  float d  = sqrtf(dx*dx+dy*dy+dz*dz + 1e-12f);
  if (d >= RCUT) return;
  int p = atomicAdd(&cursor[r], 1);
  int slot = offsets[r] + p;
  float inv_d = 1.0f/d;
  float sh[16];
  compute_sh(dx*inv_d, dy*inv_d, dz*inv_d, sh);
  float fc = 0.5f*(cosf(d*(3.14159265358979323846f/RCUT))+1.0f);
  float b[8];
  #pragma unroll
  for (int q=0;q<NB;++q){
    float t = (d - (float)((double)q*(5.0/7.0))) * 1.6f;  // sigma=0.625
    b[q] = expf(-0.5f*t*t)*fc;
  }
  float* g = geomArr + (size_t)slot*GSTRIDE;
  #pragma unroll
  for (int i=0;i<16;++i) g[i] = sh[i];
  #pragma unroll
  for (int q=0;q<8;++q) g[16+q] = b[q];
  #pragma unroll
  for (int l=0;l<4;++l)
    #pragma unroll
    for (int n=0;n<4;++n){
      float acc=0.0f;
      #pragma unroll
      for (int q=0;q<NB;++q) acc += b[q]*Winv[l*32+q*4+n];
      g[24+l*4+n] = acc;
    }
  bucket_s[slot] = s | (species[s]<<16);   // N=10000 < 2^16
}

// ---------------- kernel A: ONE-WAVE BLOCK per atom, 2-deep prefetch, K-MAJOR out -----------
__global__ __launch_bounds__(64) void kA_gather_tp(
    const float* __restrict__ emb, const int* __restrict__ species,
    const int* __restrict__ offsets, const int* __restrict__ counts,
    const int* __restrict__ bucket_s, const float* __restrict__ geomArr,
    float* __restrict__ feats, int N)
{
  int r = blockIdx.x;
  if (r >= N) return;
  int lane = threadIdx.x;
  int n = lane>>4, c = lane&15;
  int off = offsets[r], cnt = counts[r];
  float f[16];
  #pragma unroll
  for (int lm=0; lm<16; ++lm) f[lm]=0.0f;

  // prefetch stage: edge 0
  float e5_c = 0.0f;
  float4 s0c{},s1c{},s2c{},s3c{};
  float R0c=0,R1c=0,R2c=0,R3c=0;
  if (cnt>0){
    int pk = bucket_s[off];
    e5_c = 0.5f*emb[(pk>>16)*NCH+c];
    const float* gm = geomArr + (size_t)off*GSTRIDE;
    s0c=*(const float4*)(gm+0); s1c=*(const float4*)(gm+4);
    s2c=*(const float4*)(gm+8); s3c=*(const float4*)(gm+12);
    R0c=gm[24+0+n]; R1c=gm[24+4+n]; R2c=gm[24+8+n]; R3c=gm[24+12+n];
  }
  for (int j=0; j<cnt; ++j){
    bool hn = (j+1<cnt);
    int pk_n = hn ? bucket_s[off+j+1] : 0;
    float e5_n = hn ? 0.5f*emb[(pk_n>>16)*NCH+c] : 0.0f;
    const float* gn = geomArr + (size_t)(off+(hn?j+1:j))*GSTRIDE;
    float4 s0n=*(const float4*)(gn+0), s1n=*(const float4*)(gn+4);
    float4 s2n=*(const float4*)(gn+8), s3n=*(const float4*)(gn+12);
    float R0n=gn[24+0+n], R1n=gn[24+4+n], R2n=gn[24+8+n], R3n=gn[24+12+n];

    float t0 = R0c*e5_c, t1 = R1c*e5_c, t2 = R2c*e5_c, t3 = R3c*e5_c;
    f[0] += s0c.x*t0;
    f[1] += s0c.y*t1;  f[2] += s0c.z*t1;  f[3] += s0c.w*t1;
    f[4] += s1c.x*t2;  f[5] += s1c.y*t2;  f[6] += s1c.z*t2;  f[7] += s1c.w*t2;  f[8] += s2c.x*t2;
    f[9] += s2c.y*t3;  f[10]+= s2c.z*t3;  f[11]+= s2c.w*t3;
    f[12]+= s3c.x*t3;  f[13]+= s3c.y*t3;  f[14]+= s3c.z*t3;  f[15]+= s3c.w*t3;

    e5_c=e5_n; s0c=s0n; s1c=s1n; s2c=s2n; s3c=s3n;
    R0c=R0n; R1c=R1n; R2c=R2n; R3c=R3n;
  }
  // symmetric tensor product per lane
  float g[16];
  g[0]=tp_row<0>(f);  g[1]=tp_row<1>(f);  g[2]=tp_row<2>(f);  g[3]=tp_row<3>(f);
  g[4]=tp_row<4>(f);  g[5]=tp_row<5>(f);  g[6]=tp_row<6>(f);  g[7]=tp_row<7>(f);
  g[8]=tp_row<8>(f);  g[9]=tp_row<9>(f);  g[10]=tp_row<10>(f); g[11]=tp_row<11>(f);
  g[12]=tp_row<12>(f); g[13]=tp_row<13>(f); g[14]=tp_row<14>(f); g[15]=tp_row<15>(f);
  float ek = emb[species[r]*NCH + c];
  // K-MAJOR write: lane's 16 outputs are contiguous -> 4 dwordx4 stores
  float* fp = feats + (size_t)r*(LMDIM*KDIM) + lane*LMDIM;
  float4* fp4 = (float4*)fp;
  fp4[0] = make_float4((f[0]+g[0])*ek,  (f[1]+g[1])*ek,  (f[2]+g[2])*ek,  (f[3]+g[3])*ek);
  fp4[1] = make_float4((f[4]+g[4])*ek,  (f[5]+g[5])*ek,  (f[6]+g[6])*ek,  (f[7]+g[7])*ek);
  fp4[2] = make_float4((f[8]+g[8])*ek,  (f[9]+g[9])*ek,  (f[10]+g[10])*ek,(f[11]+g[11])*ek);
  fp4[3] = make_float4((f[12]+g[12])*ek,(f[13]+g[13])*ek,(f[14]+g[14])*ek,(f[15]+g[15])*ek);
}

// ---------------- kernel B: ONE-WAVE BLOCK per atom, K-MAJOR nb gather (4x dwordx4) ---------
__global__ __launch_bounds__(64) void kB_mp2_mlp(
    const float* __restrict__ Weq,
    const float* __restrict__ W1, const float* __restrict__ W2,
    const float* __restrict__ wl,
    const int* __restrict__ offsets, const int* __restrict__ counts,
    const int* __restrict__ bucket_s, const float* __restrict__ geomArr,
    const float* __restrict__ embedded, float* __restrict__ eatom, int N)
{
  __shared__ __align__(16) float Arow[256];   // 1 KB/block
  int r = blockIdx.x;
  if (r >= N) return;
  int k = threadIdx.x;
  int off = offsets[r], cnt = counts[r];
  // hoist Weq column k into registers (once per wave)
  float Wq[4][8];
  #pragma unroll
  for (int L=0;L<4;++L)
    #pragma unroll
    for (int q=0;q<8;++q)
      Wq[L][q] = Weq[L*(NB*KDIM) + q*KDIM + k];
  float m[16];
  #pragma unroll
  for (int i=0;i<16;++i) m[i]=0.0f;

  // prefetch edge 0's nb: K-MAJOR -> 4 contiguous float4 per lane
  float4 nb0c{}, nb1c{}, nb2c{}, nb3c{};
  {
    int pk0 = (cnt>0)? bucket_s[off] : 0;
    const float4* np0 = (const float4*)(embedded + (size_t)(pk0 & 0xFFFF)*(LMDIM*KDIM) + k*LMDIM);
    if (cnt>0){ nb0c=np0[0]; nb1c=np0[1]; nb2c=np0[2]; nb3c=np0[3]; }
  }
  for (int j=0; j<cnt; ++j){
    bool hn = (j+1<cnt);
    int pk_n = hn ? bucket_s[off+j+1] : 0;
    const float4* npn = (const float4*)(embedded + (size_t)(pk_n & 0xFFFF)*(LMDIM*KDIM) + k*LMDIM);
    float4 nb0n{}, nb1n{}, nb2n{}, nb3n{};
    if (hn){ nb0n=npn[0]; nb1n=npn[1]; nb2n=npn[2]; nb3n=npn[3]; }

    const float* gm = geomArr + (size_t)(off+j)*GSTRIDE;
    float4 s0 = *(const float4*)(gm+0);
    float4 s1 = *(const float4*)(gm+4);
    float4 s2 = *(const float4*)(gm+8);
    float4 s3 = *(const float4*)(gm+12);
    float4 b0 = *(const float4*)(gm+16);
    float4 b1 = *(const float4*)(gm+20);
    float sh[16] = {s0.x,s0.y,s0.z,s0.w, s1.x,s1.y,s1.z,s1.w,
                    s2.x,s2.y,s2.z,s2.w, s3.x,s3.y,s3.z,s3.w};
    float b[8] = {b0.x,b0.y,b0.z,b0.w, b1.x,b1.y,b1.z,b1.w};
    float Req[4];
    #pragma unroll
    for (int L=0;L<4;++L){
      float acc=0.0f;
      #pragma unroll
      for (int q=0;q<8;++q) acc += b[q]*Wq[L][q];
      Req[L]=acc;
    }
    // cooperative A build: lane k computes entries k,64+k,128+k,192+k
    #pragma unroll
    for (int q=0;q<4;++q){
      int ent = q*64 + k;
      const float4* c4 = (const float4*)CFLAT.v[ent];
      float4 c0=c4[0], c1=c4[1], c2=c4[2], c3=c4[3];
      float acc = c0.x*sh[0]+c0.y*sh[1]+c0.z*sh[2]+c0.w*sh[3]
                + c1.x*sh[4]+c1.y*sh[5]+c1.z*sh[6]+c1.w*sh[7]
                + c2.x*sh[8]+c2.y*sh[9]+c2.z*sh[10]+c2.w*sh[11]
                + c3.x*sh[12]+c3.y*sh[13]+c3.z*sh[14]+c3.w*sh[15];
      Arow[ent] = acc;
    }
    float nb_c[16] = {nb0c.x,nb0c.y,nb0c.z,nb0c.w, nb1c.x,nb1c.y,nb1c.z,nb1c.w,
                      nb2c.x,nb2c.y,nb2c.z,nb2c.w, nb3c.x,nb3c.y,nb3c.z,nb3c.w};
    // same-wave LDS RAW -> compiler lgkmcnt (single wave per block, no barrier needed)
    #pragma unroll
    for (int M=0;M<16;++M){
      const int L = (M==0)?0 : (M<4)?1 : (M<9)?2 : 3;
      const float4* a4 = (const float4*)(Arow + M*16);
      float4 a0=a4[0], a1=a4[1], a2=a4[2], a3=a4[3];
      float acc = a0.x*nb_c[0]+a0.y*nb_c[1]+a0.z*nb_c[2]+a0.w*nb_c[3]
                + a1.x*nb_c[4]+a1.y*nb_c[5]+a1.z*nb_c[6]+a1.w*nb_c[7]
                + a2.x*nb_c[8]+a2.y*nb_c[9]+a2.z*nb_c[10]+a2.w*nb_c[11]
                + a3.x*nb_c[12]+a3.y*nb_c[13]+a3.z*nb_c[14]+a3.w*nb_c[15];
      m[M] += acc*Req[L];
    }
    nb0c=nb0n; nb1c=nb1n; nb2c=nb2n; nb3c=nb3n;
  }

  // invariants (0.5 MP_SCALING folded into CFLAT -> m)
  float inv = m[0];
  inv += inv_term<0>(m);
  inv += inv_term<1>(m);
  inv += inv_term<2>(m);
  inv += inv_term<3>(m);
  // per-wave MLP via LDS broadcast (reuse Arow: 128 of 256 floats)
  Arow[k] = inv;
  float a=0.0f;
  #pragma unroll
  for (int c=0;c<64;++c) a += Arow[c]*W1[c*64+k];
  a = a / (1.0f + expf(-a));           // silu
  Arow[64+k] = a;
  float h2=0.0f;
  #pragma unroll
  for (int c=0;c<64;++c) h2 += Arow[64+c]*W2[c*64+k];
  h2 = h2 / (1.0f + expf(-h2));
  float e = h2*wl[k];
  #pragma unroll
  for (int o=32; o>0; o>>=1) e += __shfl_down(e, o);
  if (k==0) eatom[r] = e;
}

__global__ __launch_bounds__(256) void k_reduce(const float* __restrict__ eatom,
                                                float* __restrict__ out, int N){
  __shared__ float buf[256];
  float a=0.0f;
  for (int i=threadIdx.x; i<N; i+=256) a += eatom[i];
  buf[threadIdx.x]=a;
  __syncthreads();
  #pragma unroll
  for (int o=128;o>0;o>>=1){
    if (threadIdx.x<o) buf[threadIdx.x]+=buf[threadIdx.x+o];
    __syncthreads();
  }
  if (threadIdx.x==0) out[0]=buf[0];
}

// ---------------- launch ----------------
extern "C" void kernel_launch(void* const* d_in, const int* in_sizes, int n_in,
                              void* d_out, int out_size, void* d_ws, size_t ws_size,
                              hipStream_t stream)
{
  const float* pos     = (const float*)d_in[0];
  const float* emb     = (const float*)d_in[1];
  const float* Winv    = (const float*)d_in[2];
  const float* Weq     = (const float*)d_in[3];
  const float* W1      = (const float*)d_in[4];
  const float* W2      = (const float*)d_in[5];
  const float* wl      = (const float*)d_in[6];
  const int*   species = (const int*)d_in[7];
  const int*   senders = (const int*)d_in[8];
  const int*   recv    = (const int*)d_in[9];
  int N = in_sizes[7];
  int E = in_sizes[8];

  char* ws = (char*)d_ws;
  float* feats   = (float*)ws;                                   // N*1024 f32, K-MAJOR
  float* geomArr = feats + (size_t)N*(LMDIM*KDIM);               // E*GSTRIDE f32 (worst case)
  float* eatom   = geomArr + (size_t)E*GSTRIDE;                  // N f32
  int*   counts  = (int*)(eatom + N);                            // N
  int*   cursor  = counts + N;                                   // N
  int*   offsets = cursor + N;                                   // N
  int*   bsum    = offsets + N;                                  // 256
  int*   bbase   = bsum + 256;                                   // 256
  int*   bucket_s= bbase + 256;                                  // E

  hipMemsetAsync(counts, 0, 2*(size_t)N*sizeof(int), stream);    // counts+cursor

  int ebl = (E+255)/256;
  int SB  = (N+255)/256;
  k_hist_d<<<ebl, 256, 0, stream>>>(pos, senders, recv, counts, E);
  k_scan1<<<SB, 256, 0, stream>>>(counts, offsets, bsum, N);
  k_scan2<<<1, 256, 0, stream>>>(bsum, bbase, SB);
  k_scan3<<<SB, 256, 0, stream>>>(offsets, bbase, N);
  k_geom<<<ebl, 256, 0, stream>>>(pos, Winv, species, senders, recv, offsets, cursor,
                                  bucket_s, geomArr, E);
  kA_gather_tp<<<N, 64, 0, stream>>>(emb, species, offsets, counts, bucket_s, geomArr, feats, N);
  kB_mp2_mlp<<<N, 64, 0, stream>>>(Weq, W1, W2, wl, offsets, counts, bucket_s, geomArr,
                                   feats, eatom, N);
  k_reduce<<<1, 256, 0, stream>>>(eatom, (float*)d_out, N);
}